// Round 2
// baseline (806.323 us; speedup 1.0000x reference)
//
#include <hip/hip_runtime.h>
#include <hip/hip_bf16.h>
#include <math.h>

#define N_ROWS   131072   // 8*16384
#define DIMS     64
#define NCODES   1024
#define DECAY    0.99f
#define EPSF     1e-5f

// d_out layout (float32 elements)
#define OFF_ZQ    0
#define OFF_IDX   8388608
#define OFF_LOSS  8519680
#define OFF_PERP  8519681
#define OFF_EMB   8519682
#define OFF_ECS   8585218
#define OFF_EMAW  8586242

typedef unsigned int uint;

__device__ __forceinline__ float atomic_add_f32(float* p, float v) {
  return __hip_atomic_fetch_add(p, v, __ATOMIC_RELAXED, __HIP_MEMORY_SCOPE_AGENT);
}
__device__ __forceinline__ double atomic_add_f64(double* p, double v) {
  return __hip_atomic_fetch_add(p, v, __ATOMIC_RELAXED, __HIP_MEMORY_SCOPE_AGENT);
}

// numpy pairwise_sum base case (8 <= n <= 128), n = 64: 8 strided accumulators,
// tree combine. Inputs are the already-rounded f32 products.
__device__ __forceinline__ float np_pairwise64_sq(const float* v) {
#pragma clang fp contract(off)
  float r[8];
#pragma unroll
  for (int j = 0; j < 8; ++j) r[j] = v[j] * v[j];
#pragma unroll
  for (int i = 8; i < 64; i += 8)
#pragma unroll
    for (int j = 0; j < 8; ++j) r[j] += v[i + j] * v[i + j];
  return ((r[0] + r[1]) + (r[2] + r[3])) + ((r[4] + r[5]) + (r[6] + r[7]));
}

// ---------------- K0: init ws + np-exact code norms ----------------
__global__ __launch_bounds__(256) void k0_init(const float* __restrict__ emb,
                                               float* __restrict__ ee,
                                               uint* __restrict__ cluster,
                                               float* __restrict__ dw,
                                               double* __restrict__ sq) {
  int gid = blockIdx.x * 256 + threadIdx.x;   // grid 256 -> 65536 threads
  if (gid < NCODES * DIMS) dw[gid] = 0.0f;
  if (gid < NCODES) {
    cluster[gid] = 0u;
    float ev[DIMS];
    const float4* e4 = (const float4*)(emb + (size_t)gid * DIMS);
#pragma unroll
    for (int i = 0; i < 16; ++i) {
      float4 v = e4[i];
      ev[4*i] = v.x; ev[4*i+1] = v.y; ev[4*i+2] = v.z; ev[4*i+3] = v.w;
    }
    ee[gid] = np_pairwise64_sq(ev);
  }
  if (gid == 0) { *sq = 0.0; }
}

// ---------------- K1: numpy-f32-bit-exact argmin ----------------
// d[c] = fl( fl(zz + ee[c]) - 2*dot_c ), dot_c = sequential-FMA over k (sgemm
// rank-1-update order). argmin with strict < in increasing c = numpy argmin.
__global__ __launch_bounds__(256) void k1_exact(const float* __restrict__ z,
                                                const float* __restrict__ emb,
                                                const float* __restrict__ ee,
                                                int* __restrict__ idx_out,
                                                float* __restrict__ idx_f_out) {
#pragma clang fp contract(off)
  int row = blockIdx.x * 256 + threadIdx.x;

  float zv[DIMS];
  const float4* z4 = (const float4*)(z + (size_t)row * DIMS);
#pragma unroll
  for (int i = 0; i < 16; ++i) {
    float4 v = z4[i];
    zv[4*i] = v.x; zv[4*i+1] = v.y; zv[4*i+2] = v.z; zv[4*i+3] = v.w;
  }
  float zz = np_pairwise64_sq(zv);

  float best = 3.4e38f;
  int bidx = 0;

  for (int c0 = 0; c0 < NCODES; c0 += 4) {
    // uniform addresses -> scalar (SGPR) loads of the codebook
    const float* e0 = emb + (size_t)c0 * DIMS;
    const float* e1 = e0 + DIMS;
    const float* e2 = e0 + 2 * DIMS;
    const float* e3 = e0 + 3 * DIMS;
    float a0 = 0.f, a1 = 0.f, a2 = 0.f, a3 = 0.f;
#pragma unroll
    for (int k = 0; k < DIMS; ++k) {
      a0 = fmaf(zv[k], e0[k], a0);   // sequential single-acc FMA == sgemm
      a1 = fmaf(zv[k], e1[k], a1);
      a2 = fmaf(zv[k], e2[k], a2);
      a3 = fmaf(zv[k], e3[k], a3);
    }
    float t0 = zz + ee[c0];
    float t1 = zz + ee[c0 + 1];
    float t2 = zz + ee[c0 + 2];
    float t3 = zz + ee[c0 + 3];
    float d0 = fmaf(-2.0f, a0, t0);  // fl(t - 2*dot): 2*dot exact, one rounding
    float d1 = fmaf(-2.0f, a1, t1);
    float d2 = fmaf(-2.0f, a2, t2);
    float d3 = fmaf(-2.0f, a3, t3);
    if (d0 < best) { best = d0; bidx = c0; }
    if (d1 < best) { best = d1; bidx = c0 + 1; }
    if (d2 < best) { best = d2; bidx = c0 + 2; }
    if (d3 < best) { best = d3; bidx = c0 + 3; }
  }

  idx_out[row] = bidx;
  idx_f_out[row] = (float)bidx;
}

// ---------------- K3: gather z_q, losses accum, segment sums ----------------
__global__ __launch_bounds__(256) void k3_gather(const float* __restrict__ z,
                                                 const float* __restrict__ emb,
                                                 const int* __restrict__ idx,
                                                 float* __restrict__ out_zq,
                                                 uint* __restrict__ cluster,
                                                 float* __restrict__ dw,
                                                 double* __restrict__ sq) {
  int gid = blockIdx.x * 256 + threadIdx.x;   // over N_ROWS*16 float4s
  int row = gid >> 4, d4 = gid & 15;
  int code = idx[row];

  float4 zv = ((const float4*)z)[gid];
  float4 ev = ((const float4*)emb)[code * 16 + d4];

  // z_q_st = z + (z_q - z), replicated op-for-op
  float dx = ev.x - zv.x, dy = ev.y - zv.y, dz = ev.z - zv.z, dw_ = ev.w - zv.w;
  float4 o;
  o.x = zv.x + dx; o.y = zv.y + dy; o.z = zv.z + dz; o.w = zv.w + dw_;
  ((float4*)out_zq)[gid] = o;

  float ss = dx * dx + dy * dy + dz * dz + dw_ * dw_;

  float* dwp = dw + (size_t)code * DIMS + d4 * 4;
  atomic_add_f32(dwp + 0, zv.x);
  atomic_add_f32(dwp + 1, zv.y);
  atomic_add_f32(dwp + 2, zv.z);
  atomic_add_f32(dwp + 3, zv.w);
  if (d4 == 0) atomicAdd(&cluster[code], 1u);

  // block-reduce ss -> one f64 atomic per block
  double bs = (double)ss;
#pragma unroll
  for (int o2 = 32; o2 > 0; o2 >>= 1) bs += __shfl_down(bs, o2, 64);
  __shared__ double wsum[4];
  int lane = threadIdx.x & 63, wid = threadIdx.x >> 6;
  if (lane == 0) wsum[wid] = bs;
  __syncthreads();
  if (threadIdx.x == 0) {
    double t = (wsum[0] + wsum[1]) + (wsum[2] + wsum[3]);
    atomic_add_f64(sq, t);
  }
}

// ---------------- K4: finalize (single block) ----------------
__global__ __launch_bounds__(256) void k4_finalize(const float* __restrict__ ecs_in,
                                                   const float* __restrict__ emaw_in,
                                                   const uint* __restrict__ cluster,
                                                   const float* __restrict__ dw,
                                                   const double* __restrict__ sq,
                                                   float* __restrict__ out) {
  __shared__ double red[256];
  __shared__ float lcs[NCODES];
  int t = threadIdx.x;

  double nloc = 0.0, aloc = 0.0, bloc = 0.0;
  for (int c = t; c < NCODES; c += 256) {
    float cntf = (float)cluster[c];
    float ne = ecs_in[c] * DECAY + (1.0f - DECAY) * cntf;
    out[OFF_ECS + c] = ne;
    nloc += (double)ne;
    double p = (double)cntf / (double)N_ROWS;
    double pc = p < 1e-10 ? 1e-10 : p;
    bloc += pc;
    aloc += pc * log(pc);
  }

  red[t] = nloc; __syncthreads();
  for (int s = 128; s > 0; s >>= 1) { if (t < s) red[t] += red[t + s]; __syncthreads(); }
  double n = red[0]; __syncthreads();

  red[t] = bloc; __syncthreads();
  for (int s = 128; s > 0; s >>= 1) { if (t < s) red[t] += red[t + s]; __syncthreads(); }
  double B = red[0]; __syncthreads();

  red[t] = aloc; __syncthreads();
  for (int s = 128; s > 0; s >>= 1) { if (t < s) red[t] += red[t + s]; __syncthreads(); }
  double A = red[0]; __syncthreads();

  if (t == 0) {
    double ent = -(A / B - log(B));
    out[OFF_PERP] = (float)exp(ent);
    double M = sq[0] / (double)((size_t)N_ROWS * DIMS);
    out[OFF_LOSS] = (float)(1.5 * M);   // 0.5*commitment + codebook, both = M
  }

  float nf = (float)n;
  for (int c = t; c < NCODES; c += 256) {
    float ne = out[OFF_ECS + c];
    float cs = ((ne + EPSF) / (nf + (float)NCODES * EPSF)) * nf;
    lcs[c] = cs < 0.01f ? 0.01f : cs;
  }
  __syncthreads();

  for (int i = t; i < NCODES * DIMS; i += 256) {
    int c = i >> 6;
    float nw = emaw_in[i] * DECAY + (1.0f - DECAY) * dw[i];
    out[OFF_EMAW + i] = nw;
    out[OFF_EMB + i] = nw / lcs[c];
  }
}

// ---------------- host ----------------
extern "C" void kernel_launch(void* const* d_in, const int* in_sizes, int n_in,
                              void* d_out, int out_size, void* d_ws, size_t ws_size,
                              hipStream_t stream) {
  const float* z    = (const float*)d_in[0];
  const float* emb  = (const float*)d_in[1];
  const float* ecs  = (const float*)d_in[2];
  const float* emaw = (const float*)d_in[3];
  float* out = (float*)d_out;

  char* ws = (char*)d_ws;
  double* sq    = (double*)(ws + 0);
  int*    idxw  = (int*)(ws + 16);
  uint*   clus  = (uint*)(ws + 16 + 524288);
  float*  dw    = (float*)(ws + 16 + 524288 + 4096);
  float*  ee    = (float*)(ws + 16 + 524288 + 4096 + 262144);

  k0_init<<<256, 256, 0, stream>>>(emb, ee, clus, dw, sq);
  k1_exact<<<N_ROWS / 256, 256, 0, stream>>>(z, emb, ee, idxw, out + OFF_IDX);
  k3_gather<<<(N_ROWS * 16) / 256, 256, 0, stream>>>(z, emb, idxw, out + OFF_ZQ, clus, dw, sq);
  k4_finalize<<<1, 256, 0, stream>>>(ecs, emaw, clus, dw, sq, out);
}

// Round 3
// 722.999 us; speedup vs baseline: 1.1152x; 1.1152x over previous
//
#include <hip/hip_runtime.h>
#include <hip/hip_bf16.h>
#include <math.h>

#define N_ROWS   131072   // 8*16384
#define DIMS     64
#define NCODES   1024
#define DECAY    0.99f
#define EPSF     1e-5f

// d_out layout (float32 elements)
#define OFF_ZQ    0
#define OFF_IDX   8388608
#define OFF_LOSS  8519680
#define OFF_PERP  8519681
#define OFF_EMB   8519682
#define OFF_ECS   8585218
#define OFF_EMAW  8586242

typedef unsigned int uint;

__device__ __forceinline__ float atomic_add_f32(float* p, float v) {
  return __hip_atomic_fetch_add(p, v, __ATOMIC_RELAXED, __HIP_MEMORY_SCOPE_AGENT);
}
__device__ __forceinline__ double atomic_add_f64(double* p, double v) {
  return __hip_atomic_fetch_add(p, v, __ATOMIC_RELAXED, __HIP_MEMORY_SCOPE_AGENT);
}

// numpy pairwise_sum base case (8 <= n <= 128), n = 64: 8 strided accumulators,
// tree combine. Inputs are the already-rounded f32 products.
__device__ __forceinline__ float np_pairwise64_sq(const float* v) {
#pragma clang fp contract(off)
  float r[8];
#pragma unroll
  for (int j = 0; j < 8; ++j) r[j] = v[j] * v[j];
#pragma unroll
  for (int i = 8; i < 64; i += 8)
#pragma unroll
    for (int j = 0; j < 8; ++j) r[j] += v[i + j] * v[i + j];
  return ((r[0] + r[1]) + (r[2] + r[3])) + ((r[4] + r[5]) + (r[6] + r[7]));
}

// ---------------- K0: init ws + np-exact code norms ----------------
__global__ __launch_bounds__(256) void k0_init(const float* __restrict__ emb,
                                               float* __restrict__ ee,
                                               uint* __restrict__ cluster,
                                               float* __restrict__ dw,
                                               double* __restrict__ sq,
                                               int reps) {
  int gid = blockIdx.x * 256 + threadIdx.x;   // grid 1024 -> 262144 threads
  if (gid < NCODES * DIMS * reps) dw[gid] = 0.0f;
  if (gid < NCODES) {
    cluster[gid] = 0u;
    float ev[DIMS];
    const float4* e4 = (const float4*)(emb + (size_t)gid * DIMS);
#pragma unroll
    for (int i = 0; i < 16; ++i) {
      float4 v = e4[i];
      ev[4*i] = v.x; ev[4*i+1] = v.y; ev[4*i+2] = v.z; ev[4*i+3] = v.w;
    }
    ee[gid] = np_pairwise64_sq(ev);
  }
  if (gid == 0) { *sq = 0.0; }
}

// ---------------- K1: numpy-f32-bit-exact argmin, 4 waves/row-group ----------
// Block = 256 thr = 4 waves; wave w scans codes [256w, 256w+256) for 64 rows
// (lane = row). Per-code math identical to numpy-f32:
//   d[c] = fl( fl(zz + ee[c]) - 2*dot_c ), dot_c = sequential single-acc FMA.
// Cross-chunk merge ascending with strict < == numpy first-index argmin.
#define STEP4(ZV, E0, E1, E2, E3, K) \
  a0 = fmaf(ZV.x, E0[K],   a0); a1 = fmaf(ZV.x, E1[K],   a1); \
  a2 = fmaf(ZV.x, E2[K],   a2); a3 = fmaf(ZV.x, E3[K],   a3); \
  a0 = fmaf(ZV.y, E0[K+1], a0); a1 = fmaf(ZV.y, E1[K+1], a1); \
  a2 = fmaf(ZV.y, E2[K+1], a2); a3 = fmaf(ZV.y, E3[K+1], a3); \
  a0 = fmaf(ZV.z, E0[K+2], a0); a1 = fmaf(ZV.z, E1[K+2], a1); \
  a2 = fmaf(ZV.z, E2[K+2], a2); a3 = fmaf(ZV.z, E3[K+2], a3); \
  a0 = fmaf(ZV.w, E0[K+3], a0); a1 = fmaf(ZV.w, E1[K+3], a1); \
  a2 = fmaf(ZV.w, E2[K+3], a2); a3 = fmaf(ZV.w, E3[K+3], a3);

// sequential 8-term strided square-sum chain (numpy accumulator j)
#define SQ8(A,B,C,D,E,F,G,H) \
  (((((((A*A + B*B) + C*C) + D*D) + E*E) + F*F) + G*G) + H*H)

__global__ __launch_bounds__(256) void k1_exact(const float* __restrict__ z,
                                                const float* __restrict__ emb,
                                                const float* __restrict__ ee,
                                                int* __restrict__ idx_out,
                                                float* __restrict__ idx_f_out) {
#pragma clang fp contract(off)
  __shared__ float sval[4][64];
  __shared__ int   sidx[4][64];
  int lane  = threadIdx.x & 63;
  int chunk = __builtin_amdgcn_readfirstlane(threadIdx.x >> 6);
  int row = blockIdx.x * 64 + lane;

  const float4* z4 = (const float4*)(z + (size_t)row * DIMS);
  float4 z0 = z4[0],  z1 = z4[1],  z2 = z4[2],  z3 = z4[3];
  float4 z4v = z4[4], z5 = z4[5],  z6 = z4[6],  z7 = z4[7];
  float4 z8 = z4[8],  z9 = z4[9],  z10 = z4[10], z11 = z4[11];
  float4 z12 = z4[12], z13 = z4[13], z14 = z4[14], z15 = z4[15];
  // pin the row in VGPRs: forbid rematerialization/sinking of the loads
  asm volatile("" : "+v"(z0.x), "+v"(z0.y), "+v"(z0.z), "+v"(z0.w),
                    "+v"(z1.x), "+v"(z1.y), "+v"(z1.z), "+v"(z1.w),
                    "+v"(z2.x), "+v"(z2.y), "+v"(z2.z), "+v"(z2.w),
                    "+v"(z3.x), "+v"(z3.y), "+v"(z3.z), "+v"(z3.w));
  asm volatile("" : "+v"(z4v.x), "+v"(z4v.y), "+v"(z4v.z), "+v"(z4v.w),
                    "+v"(z5.x), "+v"(z5.y), "+v"(z5.z), "+v"(z5.w),
                    "+v"(z6.x), "+v"(z6.y), "+v"(z6.z), "+v"(z6.w),
                    "+v"(z7.x), "+v"(z7.y), "+v"(z7.z), "+v"(z7.w));
  asm volatile("" : "+v"(z8.x), "+v"(z8.y), "+v"(z8.z), "+v"(z8.w),
                    "+v"(z9.x), "+v"(z9.y), "+v"(z9.z), "+v"(z9.w),
                    "+v"(z10.x), "+v"(z10.y), "+v"(z10.z), "+v"(z10.w),
                    "+v"(z11.x), "+v"(z11.y), "+v"(z11.z), "+v"(z11.w));
  asm volatile("" : "+v"(z12.x), "+v"(z12.y), "+v"(z12.z), "+v"(z12.w),
                    "+v"(z13.x), "+v"(z13.y), "+v"(z13.z), "+v"(z13.w),
                    "+v"(z14.x), "+v"(z14.y), "+v"(z14.z), "+v"(z14.w),
                    "+v"(z15.x), "+v"(z15.y), "+v"(z15.z), "+v"(z15.w));

  // zz = numpy pairwise square-sum: r[j] over elements j, j+8, ..., j+56
  float r0 = SQ8(z0.x, z2.x, z4v.x, z6.x, z8.x, z10.x, z12.x, z14.x);
  float r1 = SQ8(z0.y, z2.y, z4v.y, z6.y, z8.y, z10.y, z12.y, z14.y);
  float r2 = SQ8(z0.z, z2.z, z4v.z, z6.z, z8.z, z10.z, z12.z, z14.z);
  float r3 = SQ8(z0.w, z2.w, z4v.w, z6.w, z8.w, z10.w, z12.w, z14.w);
  float r4 = SQ8(z1.x, z3.x, z5.x, z7.x, z9.x, z11.x, z13.x, z15.x);
  float r5 = SQ8(z1.y, z3.y, z5.y, z7.y, z9.y, z11.y, z13.y, z15.y);
  float r6 = SQ8(z1.z, z3.z, z5.z, z7.z, z9.z, z11.z, z13.z, z15.z);
  float r7 = SQ8(z1.w, z3.w, z5.w, z7.w, z9.w, z11.w, z13.w, z15.w);
  float zz = ((r0 + r1) + (r2 + r3)) + ((r4 + r5) + (r6 + r7));

  float best = 3.4e38f;
  int bidx = 0;
  int cbase = chunk * 256;

  for (int cc = 0; cc < 256; cc += 4) {
    int c0 = cbase + cc;
    const float* e0 = emb + (size_t)c0 * DIMS;   // wave-uniform -> s_load
    const float* e1 = e0 + DIMS;
    const float* e2 = e0 + 2 * DIMS;
    const float* e3 = e0 + 3 * DIMS;
    float a0 = 0.f, a1 = 0.f, a2 = 0.f, a3 = 0.f;
    STEP4(z0,  e0,e1,e2,e3, 0)  STEP4(z1,  e0,e1,e2,e3, 4)
    STEP4(z2,  e0,e1,e2,e3, 8)  STEP4(z3,  e0,e1,e2,e3, 12)
    STEP4(z4v, e0,e1,e2,e3, 16) STEP4(z5,  e0,e1,e2,e3, 20)
    STEP4(z6,  e0,e1,e2,e3, 24) STEP4(z7,  e0,e1,e2,e3, 28)
    STEP4(z8,  e0,e1,e2,e3, 32) STEP4(z9,  e0,e1,e2,e3, 36)
    STEP4(z10, e0,e1,e2,e3, 40) STEP4(z11, e0,e1,e2,e3, 44)
    STEP4(z12, e0,e1,e2,e3, 48) STEP4(z13, e0,e1,e2,e3, 52)
    STEP4(z14, e0,e1,e2,e3, 56) STEP4(z15, e0,e1,e2,e3, 60)
    float t0 = zz + ee[c0];
    float t1 = zz + ee[c0 + 1];
    float t2 = zz + ee[c0 + 2];
    float t3 = zz + ee[c0 + 3];
    float d0 = fmaf(-2.0f, a0, t0);  // fl(t - 2*dot): one rounding, == numpy
    float d1 = fmaf(-2.0f, a1, t1);
    float d2 = fmaf(-2.0f, a2, t2);
    float d3 = fmaf(-2.0f, a3, t3);
    if (d0 < best) { best = d0; bidx = c0; }
    if (d1 < best) { best = d1; bidx = c0 + 1; }
    if (d2 < best) { best = d2; bidx = c0 + 2; }
    if (d3 < best) { best = d3; bidx = c0 + 3; }
  }

  sval[threadIdx.x >> 6][lane] = best;
  sidx[threadIdx.x >> 6][lane] = bidx;
  __syncthreads();
  if (threadIdx.x < 64) {
    float bv = sval[0][threadIdx.x];
    int   bi = sidx[0][threadIdx.x];
#pragma unroll
    for (int w = 1; w < 4; ++w) {
      float v = sval[w][threadIdx.x];   // ascending chunk, strict < keeps
      int   i = sidx[w][threadIdx.x];   // lowest index on exact ties
      if (v < bv) { bv = v; bi = i; }
    }
    int orow = blockIdx.x * 64 + threadIdx.x;
    idx_out[orow] = bi;
    idx_f_out[orow] = (float)bi;
  }
}

// ---------------- K3: gather z_q, losses accum, segment sums ----------------
__global__ __launch_bounds__(256) void k3_gather(const float* __restrict__ z,
                                                 const float* __restrict__ emb,
                                                 const int* __restrict__ idx,
                                                 float* __restrict__ out_zq,
                                                 uint* __restrict__ cluster,
                                                 float* __restrict__ dw,
                                                 double* __restrict__ sq,
                                                 int repmask) {
  int gid = blockIdx.x * 256 + threadIdx.x;   // over N_ROWS*16 float4s
  int row = gid >> 4, d4 = gid & 15;
  int code = idx[row];

  float4 zv = ((const float4*)z)[gid];
  float4 ev = ((const float4*)emb)[code * 16 + d4];

  // z_q_st = z + (z_q - z), replicated op-for-op
  float dx = ev.x - zv.x, dy = ev.y - zv.y, dz = ev.z - zv.z, dw_ = ev.w - zv.w;
  float4 o;
  o.x = zv.x + dx; o.y = zv.y + dy; o.z = zv.z + dz; o.w = zv.w + dw_;
  ((float4*)out_zq)[gid] = o;

  float ss = dx * dx + dy * dy + dz * dz + dw_ * dw_;

  float* dwp = dw + (size_t)(blockIdx.x & repmask) * (NCODES * DIMS)
                  + (size_t)code * DIMS + d4 * 4;
  atomic_add_f32(dwp + 0, zv.x);
  atomic_add_f32(dwp + 1, zv.y);
  atomic_add_f32(dwp + 2, zv.z);
  atomic_add_f32(dwp + 3, zv.w);
  if (d4 == 0) atomicAdd(&cluster[code], 1u);

  // block-reduce ss -> one f64 atomic per block
  double bs = (double)ss;
#pragma unroll
  for (int o2 = 32; o2 > 0; o2 >>= 1) bs += __shfl_down(bs, o2, 64);
  __shared__ double wsum[4];
  int lane = threadIdx.x & 63, wid = threadIdx.x >> 6;
  if (lane == 0) wsum[wid] = bs;
  __syncthreads();
  if (threadIdx.x == 0) {
    double t = (wsum[0] + wsum[1]) + (wsum[2] + wsum[3]);
    atomic_add_f64(sq, t);
  }
}

// ---------------- K4: finalize (single block) ----------------
__global__ __launch_bounds__(256) void k4_finalize(const float* __restrict__ ecs_in,
                                                   const float* __restrict__ emaw_in,
                                                   const uint* __restrict__ cluster,
                                                   const float* __restrict__ dw,
                                                   const double* __restrict__ sq,
                                                   float* __restrict__ out,
                                                   int reps) {
  __shared__ double red[256];
  __shared__ float lcs[NCODES];
  int t = threadIdx.x;

  double nloc = 0.0, aloc = 0.0, bloc = 0.0;
  for (int c = t; c < NCODES; c += 256) {
    float cntf = (float)cluster[c];
    float ne = ecs_in[c] * DECAY + (1.0f - DECAY) * cntf;
    out[OFF_ECS + c] = ne;
    nloc += (double)ne;
    double p = (double)cntf / (double)N_ROWS;
    double pc = p < 1e-10 ? 1e-10 : p;
    bloc += pc;
    aloc += pc * log(pc);
  }

  red[t] = nloc; __syncthreads();
  for (int s = 128; s > 0; s >>= 1) { if (t < s) red[t] += red[t + s]; __syncthreads(); }
  double n = red[0]; __syncthreads();

  red[t] = bloc; __syncthreads();
  for (int s = 128; s > 0; s >>= 1) { if (t < s) red[t] += red[t + s]; __syncthreads(); }
  double B = red[0]; __syncthreads();

  red[t] = aloc; __syncthreads();
  for (int s = 128; s > 0; s >>= 1) { if (t < s) red[t] += red[t + s]; __syncthreads(); }
  double A = red[0]; __syncthreads();

  if (t == 0) {
    double ent = -(A / B - log(B));
    out[OFF_PERP] = (float)exp(ent);
    double M = sq[0] / (double)((size_t)N_ROWS * DIMS);
    out[OFF_LOSS] = (float)(1.5 * M);   // 0.5*commitment + codebook, both = M
  }

  float nf = (float)n;
  for (int c = t; c < NCODES; c += 256) {
    float ne = out[OFF_ECS + c];
    float cs = ((ne + EPSF) / (nf + (float)NCODES * EPSF)) * nf;
    lcs[c] = cs < 0.01f ? 0.01f : cs;
  }
  __syncthreads();

  for (int i = t; i < NCODES * DIMS; i += 256) {
    int c = i >> 6;
    float s = dw[i];
    for (int r = 1; r < reps; ++r) s += dw[r * NCODES * DIMS + i];
    float nw = emaw_in[i] * DECAY + (1.0f - DECAY) * s;
    out[OFF_EMAW + i] = nw;
    out[OFF_EMB + i] = nw / lcs[c];
  }
}

// ---------------- host ----------------
extern "C" void kernel_launch(void* const* d_in, const int* in_sizes, int n_in,
                              void* d_out, int out_size, void* d_ws, size_t ws_size,
                              hipStream_t stream) {
  const float* z    = (const float*)d_in[0];
  const float* emb  = (const float*)d_in[1];
  const float* ecs  = (const float*)d_in[2];
  const float* emaw = (const float*)d_in[3];
  float* out = (float*)d_out;

  char* ws = (char*)d_ws;
  double* sq    = (double*)(ws + 0);
  int*    idxw  = (int*)(ws + 16);
  uint*   clus  = (uint*)(ws + 16 + 524288);
  float*  dw    = (float*)(ws + 16 + 524288 + 4096);

  // dw replicas to cut f32-atomic contention; fall back if ws is small
  size_t need4 = 16 + 524288 + 4096 + 4 * 262144 + 4096;
  int reps = (ws_size >= need4) ? 4 : 1;
  float* ee = (float*)(ws + 16 + 524288 + 4096 + (size_t)reps * 262144);

  k0_init<<<1024, 256, 0, stream>>>(emb, ee, clus, dw, sq, reps);
  k1_exact<<<N_ROWS / 64, 256, 0, stream>>>(z, emb, ee, idxw, out + OFF_IDX);
  k3_gather<<<(N_ROWS * 16) / 256, 256, 0, stream>>>(z, emb, idxw, out + OFF_ZQ,
                                                     clus, dw, sq, reps - 1);
  k4_finalize<<<1, 256, 0, stream>>>(ecs, emaw, clus, dw, sq, out, reps);
}

// Round 4
// 459.739 us; speedup vs baseline: 1.7539x; 1.5726x over previous
//
#include <hip/hip_runtime.h>
#include <hip/hip_bf16.h>
#include <math.h>

#define N_ROWS   131072   // 8*16384
#define DIMS     64
#define NCODES   1024
#define DECAY    0.99f
#define EPSF     1e-5f

// d_out layout (float32 elements)
#define OFF_ZQ    0
#define OFF_IDX   8388608
#define OFF_LOSS  8519680
#define OFF_PERP  8519681
#define OFF_EMB   8519682
#define OFF_ECS   8585218
#define OFF_EMAW  8586242

typedef unsigned int uint;

__device__ __forceinline__ float atomic_add_f32(float* p, float v) {
  return __hip_atomic_fetch_add(p, v, __ATOMIC_RELAXED, __HIP_MEMORY_SCOPE_AGENT);
}
__device__ __forceinline__ double atomic_add_f64(double* p, double v) {
  return __hip_atomic_fetch_add(p, v, __ATOMIC_RELAXED, __HIP_MEMORY_SCOPE_AGENT);
}

// numpy pairwise_sum base case (8 <= n <= 128), n = 64: 8 strided accumulators,
// tree combine. Inputs are the already-rounded f32 products.
__device__ __forceinline__ float np_pairwise64_sq(const float* v) {
#pragma clang fp contract(off)
  float r[8];
#pragma unroll
  for (int j = 0; j < 8; ++j) r[j] = v[j] * v[j];
#pragma unroll
  for (int i = 8; i < 64; i += 8)
#pragma unroll
    for (int j = 0; j < 8; ++j) r[j] += v[i + j] * v[i + j];
  return ((r[0] + r[1]) + (r[2] + r[3])) + ((r[4] + r[5]) + (r[6] + r[7]));
}

// ---------------- K0: init ws + np-exact code norms ----------------
__global__ __launch_bounds__(256) void k0_init(const float* __restrict__ emb,
                                               float* __restrict__ ee,
                                               uint* __restrict__ cluster,
                                               float* __restrict__ dw,
                                               double* __restrict__ sq,
                                               int reps) {
  int gid = blockIdx.x * 256 + threadIdx.x;   // grid 1024 -> 262144 threads
  if (gid < NCODES * DIMS * reps) dw[gid] = 0.0f;
  if (gid < NCODES) {
    cluster[gid] = 0u;
    float ev[DIMS];
    const float4* e4 = (const float4*)(emb + (size_t)gid * DIMS);
#pragma unroll
    for (int i = 0; i < 16; ++i) {
      float4 v = e4[i];
      ev[4*i] = v.x; ev[4*i+1] = v.y; ev[4*i+2] = v.z; ev[4*i+3] = v.w;
    }
    ee[gid] = np_pairwise64_sq(ev);
  }
  if (gid == 0) { *sq = 0.0; }
}

// ---------------- K1: numpy-f32-bit-exact argmin, 4 waves/row-group ----------
// Block = 256 thr = 4 waves; wave w scans codes [256w, 256w+256) for 64 rows
// (lane = row). Per-code math identical to numpy-f32:
//   d[c] = fl( fl(zz + ee[c]) - 2*dot_c ), dot_c = sequential single-acc FMA.
// Cross-chunk merge ascending with strict < == numpy first-index argmin.
#define STEP4(ZV, E0, E1, E2, E3, K) \
  a0 = fmaf(ZV.x, E0[K],   a0); a1 = fmaf(ZV.x, E1[K],   a1); \
  a2 = fmaf(ZV.x, E2[K],   a2); a3 = fmaf(ZV.x, E3[K],   a3); \
  a0 = fmaf(ZV.y, E0[K+1], a0); a1 = fmaf(ZV.y, E1[K+1], a1); \
  a2 = fmaf(ZV.y, E2[K+1], a2); a3 = fmaf(ZV.y, E3[K+1], a3); \
  a0 = fmaf(ZV.z, E0[K+2], a0); a1 = fmaf(ZV.z, E1[K+2], a1); \
  a2 = fmaf(ZV.z, E2[K+2], a2); a3 = fmaf(ZV.z, E3[K+2], a3); \
  a0 = fmaf(ZV.w, E0[K+3], a0); a1 = fmaf(ZV.w, E1[K+3], a1); \
  a2 = fmaf(ZV.w, E2[K+3], a2); a3 = fmaf(ZV.w, E3[K+3], a3);

// sequential 8-term strided square-sum chain (numpy accumulator j)
#define SQ8(A,B,C,D,E,F,G,H) \
  (((((((A*A + B*B) + C*C) + D*D) + E*E) + F*F) + G*G) + H*H)

__global__ __launch_bounds__(256) void k1_exact(const float* __restrict__ z,
                                                const float* __restrict__ emb,
                                                const float* __restrict__ ee,
                                                int* __restrict__ idx_out,
                                                float* __restrict__ idx_f_out) {
#pragma clang fp contract(off)
  __shared__ float sval[4][64];
  __shared__ int   sidx[4][64];
  int lane  = threadIdx.x & 63;
  int chunk = __builtin_amdgcn_readfirstlane(threadIdx.x >> 6);
  int row = blockIdx.x * 64 + lane;

  const float4* z4 = (const float4*)(z + (size_t)row * DIMS);
  float4 z0 = z4[0],  z1 = z4[1],  z2 = z4[2],  z3 = z4[3];
  float4 z4v = z4[4], z5 = z4[5],  z6 = z4[6],  z7 = z4[7];
  float4 z8 = z4[8],  z9 = z4[9],  z10 = z4[10], z11 = z4[11];
  float4 z12 = z4[12], z13 = z4[13], z14 = z4[14], z15 = z4[15];
  // pin the row in VGPRs: forbid rematerialization/sinking of the loads
  asm volatile("" : "+v"(z0.x), "+v"(z0.y), "+v"(z0.z), "+v"(z0.w),
                    "+v"(z1.x), "+v"(z1.y), "+v"(z1.z), "+v"(z1.w),
                    "+v"(z2.x), "+v"(z2.y), "+v"(z2.z), "+v"(z2.w),
                    "+v"(z3.x), "+v"(z3.y), "+v"(z3.z), "+v"(z3.w));
  asm volatile("" : "+v"(z4v.x), "+v"(z4v.y), "+v"(z4v.z), "+v"(z4v.w),
                    "+v"(z5.x), "+v"(z5.y), "+v"(z5.z), "+v"(z5.w),
                    "+v"(z6.x), "+v"(z6.y), "+v"(z6.z), "+v"(z6.w),
                    "+v"(z7.x), "+v"(z7.y), "+v"(z7.z), "+v"(z7.w));
  asm volatile("" : "+v"(z8.x), "+v"(z8.y), "+v"(z8.z), "+v"(z8.w),
                    "+v"(z9.x), "+v"(z9.y), "+v"(z9.z), "+v"(z9.w),
                    "+v"(z10.x), "+v"(z10.y), "+v"(z10.z), "+v"(z10.w),
                    "+v"(z11.x), "+v"(z11.y), "+v"(z11.z), "+v"(z11.w));
  asm volatile("" : "+v"(z12.x), "+v"(z12.y), "+v"(z12.z), "+v"(z12.w),
                    "+v"(z13.x), "+v"(z13.y), "+v"(z13.z), "+v"(z13.w),
                    "+v"(z14.x), "+v"(z14.y), "+v"(z14.z), "+v"(z14.w),
                    "+v"(z15.x), "+v"(z15.y), "+v"(z15.z), "+v"(z15.w));

  // zz = numpy pairwise square-sum: r[j] over elements j, j+8, ..., j+56
  float r0 = SQ8(z0.x, z2.x, z4v.x, z6.x, z8.x, z10.x, z12.x, z14.x);
  float r1 = SQ8(z0.y, z2.y, z4v.y, z6.y, z8.y, z10.y, z12.y, z14.y);
  float r2 = SQ8(z0.z, z2.z, z4v.z, z6.z, z8.z, z10.z, z12.z, z14.z);
  float r3 = SQ8(z0.w, z2.w, z4v.w, z6.w, z8.w, z10.w, z12.w, z14.w);
  float r4 = SQ8(z1.x, z3.x, z5.x, z7.x, z9.x, z11.x, z13.x, z15.x);
  float r5 = SQ8(z1.y, z3.y, z5.y, z7.y, z9.y, z11.y, z13.y, z15.y);
  float r6 = SQ8(z1.z, z3.z, z5.z, z7.z, z9.z, z11.z, z13.z, z15.z);
  float r7 = SQ8(z1.w, z3.w, z5.w, z7.w, z9.w, z11.w, z13.w, z15.w);
  float zz = ((r0 + r1) + (r2 + r3)) + ((r4 + r5) + (r6 + r7));

  float best = 3.4e38f;
  int bidx = 0;
  int cbase = chunk * 256;

  for (int cc = 0; cc < 256; cc += 4) {
    int c0 = cbase + cc;
    const float* e0 = emb + (size_t)c0 * DIMS;   // wave-uniform -> s_load
    const float* e1 = e0 + DIMS;
    const float* e2 = e0 + 2 * DIMS;
    const float* e3 = e0 + 3 * DIMS;
    float a0 = 0.f, a1 = 0.f, a2 = 0.f, a3 = 0.f;
    STEP4(z0,  e0,e1,e2,e3, 0)  STEP4(z1,  e0,e1,e2,e3, 4)
    STEP4(z2,  e0,e1,e2,e3, 8)  STEP4(z3,  e0,e1,e2,e3, 12)
    STEP4(z4v, e0,e1,e2,e3, 16) STEP4(z5,  e0,e1,e2,e3, 20)
    STEP4(z6,  e0,e1,e2,e3, 24) STEP4(z7,  e0,e1,e2,e3, 28)
    STEP4(z8,  e0,e1,e2,e3, 32) STEP4(z9,  e0,e1,e2,e3, 36)
    STEP4(z10, e0,e1,e2,e3, 40) STEP4(z11, e0,e1,e2,e3, 44)
    STEP4(z12, e0,e1,e2,e3, 48) STEP4(z13, e0,e1,e2,e3, 52)
    STEP4(z14, e0,e1,e2,e3, 56) STEP4(z15, e0,e1,e2,e3, 60)
    float t0 = zz + ee[c0];
    float t1 = zz + ee[c0 + 1];
    float t2 = zz + ee[c0 + 2];
    float t3 = zz + ee[c0 + 3];
    float d0 = fmaf(-2.0f, a0, t0);  // fl(t - 2*dot): one rounding, == numpy
    float d1 = fmaf(-2.0f, a1, t1);
    float d2 = fmaf(-2.0f, a2, t2);
    float d3 = fmaf(-2.0f, a3, t3);
    if (d0 < best) { best = d0; bidx = c0; }
    if (d1 < best) { best = d1; bidx = c0 + 1; }
    if (d2 < best) { best = d2; bidx = c0 + 2; }
    if (d3 < best) { best = d3; bidx = c0 + 3; }
  }

  sval[threadIdx.x >> 6][lane] = best;
  sidx[threadIdx.x >> 6][lane] = bidx;
  __syncthreads();
  if (threadIdx.x < 64) {
    float bv = sval[0][threadIdx.x];
    int   bi = sidx[0][threadIdx.x];
#pragma unroll
    for (int w = 1; w < 4; ++w) {
      float v = sval[w][threadIdx.x];   // ascending chunk, strict < keeps
      int   i = sidx[w][threadIdx.x];   // lowest index on exact ties
      if (v < bv) { bv = v; bi = i; }
    }
    int orow = blockIdx.x * 64 + threadIdx.x;
    idx_out[orow] = bi;
    idx_f_out[orow] = (float)bi;
  }
}

// ---------------- K3: gather z_q, losses accum, segment sums ----------------
__global__ __launch_bounds__(256) void k3_gather(const float* __restrict__ z,
                                                 const float* __restrict__ emb,
                                                 const int* __restrict__ idx,
                                                 float* __restrict__ out_zq,
                                                 uint* __restrict__ cluster,
                                                 float* __restrict__ dw,
                                                 double* __restrict__ sq,
                                                 int repmask) {
  int gid = blockIdx.x * 256 + threadIdx.x;   // over N_ROWS*16 float4s
  int row = gid >> 4, d4 = gid & 15;
  int code = idx[row];

  float4 zv = ((const float4*)z)[gid];
  float4 ev = ((const float4*)emb)[code * 16 + d4];

  // z_q_st = z + (z_q - z), replicated op-for-op
  float dx = ev.x - zv.x, dy = ev.y - zv.y, dz = ev.z - zv.z, dw_ = ev.w - zv.w;
  float4 o;
  o.x = zv.x + dx; o.y = zv.y + dy; o.z = zv.z + dz; o.w = zv.w + dw_;
  ((float4*)out_zq)[gid] = o;

  float ss = dx * dx + dy * dy + dz * dz + dw_ * dw_;

  float* dwp = dw + (size_t)(blockIdx.x & repmask) * (NCODES * DIMS)
                  + (size_t)code * DIMS + d4 * 4;
  atomic_add_f32(dwp + 0, zv.x);
  atomic_add_f32(dwp + 1, zv.y);
  atomic_add_f32(dwp + 2, zv.z);
  atomic_add_f32(dwp + 3, zv.w);
  if (d4 == 0) atomicAdd(&cluster[code], 1u);

  // block-reduce ss -> one f64 atomic per block
  double bs = (double)ss;
#pragma unroll
  for (int o2 = 32; o2 > 0; o2 >>= 1) bs += __shfl_down(bs, o2, 64);
  __shared__ double wsum[4];
  int lane = threadIdx.x & 63, wid = threadIdx.x >> 6;
  if (lane == 0) wsum[wid] = bs;
  __syncthreads();
  if (threadIdx.x == 0) {
    double t = (wsum[0] + wsum[1]) + (wsum[2] + wsum[3]);
    atomic_add_f64(sq, t);
  }
}

// ---------------- K4a: serial finalize (1 block): ecs, n, loss, perp, cs ----
__global__ __launch_bounds__(256) void k4a_scalar(const float* __restrict__ ecs_in,
                                                  const uint* __restrict__ cluster,
                                                  const double* __restrict__ sq,
                                                  float* __restrict__ csb,
                                                  float* __restrict__ out) {
  __shared__ double red[256];
  int t = threadIdx.x;

  double nloc = 0.0, aloc = 0.0, bloc = 0.0;
  for (int c = t; c < NCODES; c += 256) {
    float cntf = (float)cluster[c];
    float ne = ecs_in[c] * DECAY + (1.0f - DECAY) * cntf;
    out[OFF_ECS + c] = ne;
    nloc += (double)ne;
    double p = (double)cntf / (double)N_ROWS;
    double pc = p < 1e-10 ? 1e-10 : p;
    bloc += pc;
    aloc += pc * log(pc);
  }

  red[t] = nloc; __syncthreads();
  for (int s = 128; s > 0; s >>= 1) { if (t < s) red[t] += red[t + s]; __syncthreads(); }
  double n = red[0]; __syncthreads();

  red[t] = bloc; __syncthreads();
  for (int s = 128; s > 0; s >>= 1) { if (t < s) red[t] += red[t + s]; __syncthreads(); }
  double B = red[0]; __syncthreads();

  red[t] = aloc; __syncthreads();
  for (int s = 128; s > 0; s >>= 1) { if (t < s) red[t] += red[t + s]; __syncthreads(); }
  double A = red[0]; __syncthreads();

  if (t == 0) {
    double ent = -(A / B - log(B));
    out[OFF_PERP] = (float)exp(ent);
    double M = sq[0] / (double)((size_t)N_ROWS * DIMS);
    out[OFF_LOSS] = (float)(1.5 * M);   // 0.5*commitment + codebook, both = M
  }

  float nf = (float)n;
  for (int c = t; c < NCODES; c += 256) {
    float ne = out[OFF_ECS + c];
    float cs = ((ne + EPSF) / (nf + (float)NCODES * EPSF)) * nf;
    csb[c] = cs < 0.01f ? 0.01f : cs;
  }
}

// ---------------- K4b: parallel finalize: ema_w + embedding ----------------
__global__ __launch_bounds__(256) void k4b_emb(const float* __restrict__ emaw_in,
                                               const float* __restrict__ dw,
                                               const float* __restrict__ csb,
                                               float* __restrict__ out,
                                               int reps) {
  int i = blockIdx.x * 256 + threadIdx.x;   // grid 256 -> 65536 threads
  int c = i >> 6;
  float s = dw[i];
  for (int r = 1; r < reps; ++r) s += dw[r * NCODES * DIMS + i];
  float nw = emaw_in[i] * DECAY + (1.0f - DECAY) * s;
  out[OFF_EMAW + i] = nw;
  out[OFF_EMB + i] = nw / csb[c];
}

// ---------------- host ----------------
extern "C" void kernel_launch(void* const* d_in, const int* in_sizes, int n_in,
                              void* d_out, int out_size, void* d_ws, size_t ws_size,
                              hipStream_t stream) {
  const float* z    = (const float*)d_in[0];
  const float* emb  = (const float*)d_in[1];
  const float* ecs  = (const float*)d_in[2];
  const float* emaw = (const float*)d_in[3];
  float* out = (float*)d_out;

  char* ws = (char*)d_ws;
  double* sq    = (double*)(ws + 0);
  int*    idxw  = (int*)(ws + 16);
  uint*   clus  = (uint*)(ws + 16 + 524288);
  float*  dw    = (float*)(ws + 16 + 524288 + 4096);

  // dw replicas to cut f32-atomic contention; fall back if ws is small
  size_t need4 = 16 + 524288 + 4096 + 4 * 262144 + 8192;
  int reps = (ws_size >= need4) ? 4 : 1;
  float* ee  = (float*)(ws + 16 + 524288 + 4096 + (size_t)reps * 262144);
  float* csb = ee + NCODES;

  k0_init<<<1024, 256, 0, stream>>>(emb, ee, clus, dw, sq, reps);
  k1_exact<<<N_ROWS / 64, 256, 0, stream>>>(z, emb, ee, idxw, out + OFF_IDX);
  k3_gather<<<(N_ROWS * 16) / 256, 256, 0, stream>>>(z, emb, idxw, out + OFF_ZQ,
                                                     clus, dw, sq, reps - 1);
  k4a_scalar<<<1, 256, 0, stream>>>(ecs, clus, sq, csb, out);
  k4b_emb<<<256, 256, 0, stream>>>(emaw, dw, csb, out, reps);
}